// Round 1
// baseline (125.811 us; speedup 1.0000x reference)
//
#include <hip/hip_runtime.h>
#include <hip/hip_bf16.h>

#define BATCH   2048
#define NFIELDS 32
#define EMBED   64
#define NPAIRS  496

typedef __attribute__((ext_vector_type(8))) short bf16x8;
typedef __attribute__((ext_vector_type(4))) float f32x4;

__device__ __forceinline__ unsigned short f2bf(float x) {
    unsigned int u = __float_as_uint(x);
    unsigned int r = 0x7fffu + ((u >> 16) & 1u);
    return (unsigned short)((u + r) >> 16);
}
__device__ __forceinline__ bf16x8 cvt8(const float* p) {
    float4 v0 = *(const float4*)p;
    float4 v1 = *(const float4*)(p + 4);
    bf16x8 o;
    o[0]=(short)f2bf(v0.x); o[1]=(short)f2bf(v0.y); o[2]=(short)f2bf(v0.z); o[3]=(short)f2bf(v0.w);
    o[4]=(short)f2bf(v1.x); o[5]=(short)f2bf(v1.y); o[6]=(short)f2bf(v1.z); o[7]=(short)f2bf(v1.w);
    return o;
}

// Prepass: emb fp32 -> bf16 (same layout); kernel fp32 [i][p][j] -> bf16 [p][i][j]
__global__ __launch_bounds__(256) void convert_prepass(
    const float* __restrict__ emb, const float* __restrict__ kern,
    unsigned short* __restrict__ embB, unsigned short* __restrict__ kernB)
{
    const int EMB4 = BATCH * NFIELDS * EMBED / 4;   // 1048576
    const int KER4 = EMBED * NPAIRS * EMBED / 4;    // 507904
    int t = blockIdx.x * blockDim.x + threadIdx.x;
    if (t < EMB4) {
        float4 v = ((const float4*)emb)[t];
        ushort4 o;
        o.x = f2bf(v.x); o.y = f2bf(v.y); o.z = f2bf(v.z); o.w = f2bf(v.w);
        *(ushort4*)(embB + (size_t)t * 4) = o;
    } else if (t < EMB4 + KER4) {
        int u = t - EMB4;
        int j4   = u & 15;
        int rest = u >> 4;
        int p = rest % NPAIRS;
        int i = rest / NPAIRS;
        float4 v = *(const float4*)(kern + (size_t)i * (NPAIRS*EMBED) + (size_t)p * EMBED + j4*4);
        ushort4 o;
        o.x = f2bf(v.x); o.y = f2bf(v.y); o.z = f2bf(v.z); o.w = f2bf(v.w);
        *(ushort4*)(kernB + (size_t)p * 4096 + i * 64 + j4 * 4) = o;
    }
}

// Main: block = (4-pair chunk, batch-tile of 128). 4 waves; wave w owns pair chunk*4+w
// across all 128 batches of the tile (8 sub-tiles of 16).
// MFMA computes D[m=i][n=batch] = sum_j K_p[i,j] * emb[b, r, j]; A = K rows (in regs,
// loaded once per wave), B = emb_r rows (direct global bf16, no LDS, no barriers).
// Epilogue: q as aligned float4 from ORIGINAL fp32 emb; reduce over i = 16 fma +
// 2 shfl_xor. Output staged in tiny LDS tile for 16B-coalesced stores.
template<bool PRE>
__global__ __launch_bounds__(256) void opn_main(
    const void* __restrict__ embP, const void* __restrict__ kernP,
    const float* __restrict__ embF, float* __restrict__ out)
{
    const int chunk = blockIdx.x;          // 0..123
    const int bt    = blockIdx.y;          // 0..15
    const int tid   = threadIdx.x;
    const int wave  = tid >> 6, lane = tid & 63;
    const int col   = lane & 15, quad = lane >> 4;
    const int pair  = chunk * 4 + wave;

    // decode pair -> (r, c), triu k=1 row-major
    int r = 0, s = 0;
    while (pair >= s + (NFIELDS - 1 - r)) { s += NFIELDS - 1 - r; ++r; }
    const int c = r + 1 + (pair - s);

    __shared__ __align__(16) float Otile[128][4];

    // ---- A fragments: lane holds K_p[i = nt*16+col][j = ks*32 + quad*8 + t] ----
    bf16x8 kfr[4][2];
    if (PRE) {
        const unsigned short* kb = (const unsigned short*)kernP + (size_t)pair * 4096;
        #pragma unroll
        for (int nt = 0; nt < 4; ++nt)
            #pragma unroll
            for (int ks = 0; ks < 2; ++ks)
                kfr[nt][ks] = *(const bf16x8*)(kb + (nt*16 + col) * 64 + ks*32 + quad*8);
    } else {
        const float* kf = (const float*)kernP;
        #pragma unroll
        for (int nt = 0; nt < 4; ++nt)
            #pragma unroll
            for (int ks = 0; ks < 2; ++ks)
                kfr[nt][ks] = cvt8(kf + (size_t)(nt*16 + col) * (NPAIRS*EMBED)
                                     + (size_t)pair * EMBED + ks*32 + quad*8);
    }

    #pragma unroll 2
    for (int it = 0; it < 8; ++it) {
        const int brow = bt * 128 + it * 16 + col;

        // B fragments: emb[brow, r, j] bf16, j = ks*32 + quad*8 + t
        bf16x8 bfr0, bfr1;
        if (PRE) {
            const unsigned short* eb = (const unsigned short*)embP
                                     + ((size_t)brow * NFIELDS + r) * EMBED;
            bfr0 = *(const bf16x8*)(eb + quad*8);
            bfr1 = *(const bf16x8*)(eb + 32 + quad*8);
        } else {
            const float* ef = (const float*)embP + ((size_t)brow * NFIELDS + r) * EMBED;
            bfr0 = cvt8(ef + quad*8);
            bfr1 = cvt8(ef + 32 + quad*8);
        }

        // q: fp32 direct from original emb; lane needs q[brow][nt*16 + quad*4 .. +4]
        const float* qp = embF + ((size_t)brow * NFIELDS + c) * EMBED + quad*4;
        f32x4 q0 = *(const f32x4*)(qp);
        f32x4 q1 = *(const f32x4*)(qp + 16);
        f32x4 q2 = *(const f32x4*)(qp + 32);
        f32x4 q3 = *(const f32x4*)(qp + 48);

        float partial = 0.f;
        #pragma unroll
        for (int nt = 0; nt < 4; ++nt) {
            f32x4 acc = {0.f, 0.f, 0.f, 0.f};
            acc = __builtin_amdgcn_mfma_f32_16x16x32_bf16(kfr[nt][0], bfr0, acc, 0, 0, 0);
            acc = __builtin_amdgcn_mfma_f32_16x16x32_bf16(kfr[nt][1], bfr1, acc, 0, 0, 0);
            f32x4 qq = (nt == 0) ? q0 : (nt == 1) ? q1 : (nt == 2) ? q2 : q3;
            partial += acc[0]*qq[0] + acc[1]*qq[1] + acc[2]*qq[2] + acc[3]*qq[3];
        }
        // reduce over i: lanes {col, col+16, col+32, col+48}
        partial += __shfl_xor(partial, 16, 64);
        partial += __shfl_xor(partial, 32, 64);
        if (quad == 0) Otile[it*16 + col][wave] = partial;
    }
    __syncthreads();

    if (tid < 128) {
        f32x4 o = *(const f32x4*)&Otile[tid][0];
        *(f32x4*)&out[((size_t)(bt*128 + tid)) * NPAIRS + chunk*4] = o;
    }
}

extern "C" void kernel_launch(void* const* d_in, const int* in_sizes, int n_in,
                              void* d_out, int out_size, void* d_ws, size_t ws_size,
                              hipStream_t stream) {
    const float* emb  = (const float*)d_in[0];   // (2048, 32, 64) fp32
    const float* kern = (const float*)d_in[1];   // (64, 496, 64) fp32
    float* out = (float*)d_out;                  // (2048, 1, 496) fp32

    const size_t embElems  = (size_t)BATCH * NFIELDS * EMBED;   // 4194304
    const size_t kernElems = (size_t)EMBED * NPAIRS * EMBED;    // 2031616
    const size_t need = (embElems + kernElems) * sizeof(unsigned short);

    dim3 grid(NPAIRS / 4, BATCH / 128);          // (124, 16)
    if (ws_size >= need) {
        unsigned short* embB  = (unsigned short*)d_ws;
        unsigned short* kernB = embB + embElems;
        int total4 = (int)((embElems + kernElems) / 4);         // 1556480
        convert_prepass<<<(total4 + 255) / 256, 256, 0, stream>>>(emb, kern, embB, kernB);
        opn_main<true><<<grid, 256, 0, stream>>>((const void*)embB, (const void*)kernB, emb, out);
    } else {
        opn_main<false><<<grid, 256, 0, stream>>>((const void*)emb, (const void*)kern, emb, out);
    }
}